// Round 1
// baseline (1452.899 us; speedup 1.0000x reference)
//
#include <hip/hip_runtime.h>
#include <math.h>

#define NN 4096
#define EE 65536
#define H 128
#define NF 4
#define MNODE 8
#define MEDGE 4
#define NT 2

// ---------------- CSR build ----------------
__global__ void k_count(const int* __restrict__ dst, int* __restrict__ cnt) {
  int e = blockIdx.x * 256 + threadIdx.x;
  if (e < EE) atomicAdd(&cnt[dst[e]], 1);
}

__global__ void k_scan(const int* __restrict__ cnt, int* __restrict__ rp) {
  __shared__ int sh[1024];
  int t = threadIdx.x;
  int v0 = cnt[4*t], v1 = cnt[4*t+1], v2 = cnt[4*t+2], v3 = cnt[4*t+3];
  int p1 = v0, p2 = v0 + v1, p3 = p2 + v2, tot = p3 + v3;
  sh[t] = tot; __syncthreads();
  for (int off = 1; off < 1024; off <<= 1) {
    int add = (t >= off) ? sh[t-off] : 0;
    __syncthreads();
    sh[t] += add;
    __syncthreads();
  }
  int base = sh[t] - tot;
  rp[4*t] = base; rp[4*t+1] = base + p1; rp[4*t+2] = base + p2; rp[4*t+3] = base + p3;
  if (t == 1023) rp[NN] = sh[t];
}

__global__ void k_fill(const int* __restrict__ ei, int* __restrict__ cursor, int* __restrict__ cols) {
  int e = blockIdx.x * 256 + threadIdx.x;
  if (e < EE) {
    int d = ei[EE + e], s = ei[e];
    int pos = atomicAdd(&cursor[d], 1);
    cols[pos] = s;
  }
}

__global__ void k_dinv0(const int* __restrict__ cnt, float* __restrict__ d2, float* __restrict__ d1) {
  int i = blockIdx.x * 256 + threadIdx.x;
  if (i < NN) {
    float c = (float)cnt[i];
    d2[i] = 1.f / sqrtf(c + 2.f);
    d1[i] = 1.f / sqrtf(c + 1.f);
  }
}

__global__ void k_pwnorm(const float* __restrict__ pw, float* __restrict__ pwn) {
  int l = blockIdx.x, t = threadIdx.x; // 64 threads
  float a = pw[l*H + t], b = pw[l*H + 64 + t];
  float s = a*a + b*b;
  for (int off = 32; off > 0; off >>= 1) s += __shfl_down(s, off);
  if (t == 0) pwn[l] = sqrtf(s);
}

__global__ void k_segS(const int* __restrict__ dst, const float* __restrict__ me, float* __restrict__ S) {
  int e = blockIdx.x * 256 + threadIdx.x;
  if (e < EE) {
    int d = dst[e];
#pragma unroll
    for (int m = 0; m < MEDGE; m++) atomicAdd(&S[d*MEDGE + m], me[e*MEDGE + m]);
  }
}

// ---------------- node_attr & matmuls ----------------
__global__ void k_na(const float* __restrict__ F, const float* __restrict__ mn,
                     const float* __restrict__ h, float* __restrict__ na) {
  int idx = blockIdx.x * 256 + threadIdx.x;
  if (idx >= NN * 140) return;
  int row = idx / 140, c = idx - row * 140;
  float v;
  if (c < NF) v = F[row*NF + c];
  else if (c < NF + MNODE) v = mn[row*MNODE + (c - NF)];
  else v = h[row*H + (c - NF - MNODE)];
  na[idx] = v;
}

// C[row,0:128] = A[row,:K] @ B[:K,0:128]  (B row-stride 128); optional row scale by dinv
__global__ void k_mm_rb(const float* __restrict__ A, int lda, const float* __restrict__ B,
                        float* __restrict__ C, int K, const float* __restrict__ dinv) {
  __shared__ float as[160];
  int row = blockIdx.x, t = threadIdx.x;
  float acc = 0.f;
  for (int k0 = 0; k0 < K; k0 += H) {
    int m = (K - k0 < H) ? (K - k0) : H;
    if (t < m) as[t] = A[(size_t)row*lda + k0 + t];
    __syncthreads();
    for (int kk = 0; kk < m; kk++) acc += as[kk] * B[(k0 + kk)*H + t];
    __syncthreads();
  }
  if (dinv) acc *= dinv[row];
  C[(size_t)row*H + t] = acc;
}

// SpMM over CSR rows; if dinv!=null apply GCN epilogue: dinv_i*(acc + fill*ts_i) + bias (+relu)
__global__ void k_spmm_fused(const float* __restrict__ ts, const int* __restrict__ rp,
                             const int* __restrict__ cols, const float* __restrict__ dinv,
                             float fill, const float* __restrict__ bias, int relu,
                             float* __restrict__ out) {
  int i = blockIdx.x, t = threadIdx.x;
  float acc = 0.f;
  int beg = rp[i], end = rp[i+1];
  for (int e = beg; e < end; e++) acc += ts[(size_t)cols[e]*H + t];
  float v;
  if (dinv) {
    v = dinv[i] * (acc + fill * ts[(size_t)i*H + t]) + bias[t];
    if (relu) v = fmaxf(v, 0.f);
  } else v = acc;
  out[(size_t)i*H + t] = v;
}

__global__ void k_h1(const float* __restrict__ P, const float* __restrict__ bm,
                     const float* __restrict__ AQ, const float* __restrict__ S,
                     const float* __restrict__ WmB, const int* __restrict__ cnt,
                     float* __restrict__ h1) {
  int i = blockIdx.x, t = threadIdx.x;
  float v = (float)cnt[i] * (P[(size_t)i*H + t] + bm[t]) + AQ[(size_t)i*H + t];
#pragma unroll
  for (int m = 0; m < MEDGE; m++) v += S[i*MEDGE + m] * WmB[m*H + t];
  h1[(size_t)i*H + t] = fmaxf(v, 0.f);
}

// ---------------- top-k pooling ----------------
__global__ void k_score(const float* __restrict__ x, const float* __restrict__ pw,
                        const float* __restrict__ pwn, float* __restrict__ score) {
  int row = blockIdx.x, t = threadIdx.x; // 64 threads
  float s = x[(size_t)row*H + t]*pw[t] + x[(size_t)row*H + 64 + t]*pw[64 + t];
  for (int off = 32; off > 0; off >>= 1) s += __shfl_down(s, off);
  if (t == 0) score[row] = tanhf(s / pwn[0]);
}

__device__ __forceinline__ bool d_before(float sa, int ia, float sb, int ib) {
  return (sa > sb) || (sa == sb && ia < ib);
}

// single-block bitonic sort, descending by score, ties -> lower index (matches jax.lax.top_k)
__global__ void k_sort(const float* __restrict__ score, int n, int npow2, int k,
                       int* __restrict__ perm, float* __restrict__ sv) {
  __shared__ float ss[4096];
  __shared__ int si[4096];
  int t = threadIdx.x;
  for (int i = t; i < npow2; i += 1024) {
    ss[i] = (i < n) ? score[i] : -INFINITY;
    si[i] = (i < n) ? i : 0x7fffffff;
  }
  __syncthreads();
  for (int ksz = 2; ksz <= npow2; ksz <<= 1) {
    for (int j = ksz >> 1; j > 0; j >>= 1) {
      for (int i = t; i < npow2; i += 1024) {
        int ixj = i ^ j;
        if (ixj > i) {
          float sa = ss[i], sb = ss[ixj];
          int ia = si[i], ib = si[ixj];
          bool asc = ((i & ksz) == 0);
          bool sw = asc ? d_before(sb, ib, sa, ia) : d_before(sa, ia, sb, ib);
          if (sw) { ss[i] = sb; si[i] = ib; ss[ixj] = sa; si[ixj] = ia; }
        }
      }
      __syncthreads();
    }
  }
  for (int r = t; r < k; r += 1024) { perm[r] = si[r]; sv[r] = ss[r]; }
}

__global__ void k_poolx(const float* __restrict__ x, const int* __restrict__ perm,
                        const float* __restrict__ sv, float* __restrict__ xp) {
  int r = blockIdx.x, t = threadIdx.x;
  xp[(size_t)r*H + t] = x[(size_t)perm[r]*H + t] * sv[r];
}

// A_820[r,c] = (A1@A1)[perm_r, perm_c], diag zeroed; A1 = offdiag(A0)+I via CSR
__global__ void k_a820(const int* __restrict__ rp, const int* __restrict__ cols,
                       const int* __restrict__ perm, float* __restrict__ A820) {
  __shared__ float acc[NN];
  int r = blockIdx.x, t = threadIdx.x;
  for (int i = t; i < NN; i += 256) acc[i] = 0.f;
  __syncthreads();
  int pi = perm[r];
  int beg = rp[pi], end = rp[pi+1];
  // k = pi term: + A1[pi,:]
  for (int e = beg + t; e < end; e += 256) { int c = cols[e]; if (c != pi) atomicAdd(&acc[c], 1.f); }
  if (t == 0) atomicAdd(&acc[pi], 1.f);
  // k != pi terms: for each off-diag edge instance (pi->c): + A1[c,:]
  for (int e0 = beg; e0 < end; e0++) {
    int c = cols[e0];
    if (c == pi) continue;
    int b2 = rp[c], e2 = rp[c+1];
    for (int e = b2 + t; e < e2; e += 256) { int c2 = cols[e]; if (c2 != c) atomicAdd(&acc[c2], 1.f); }
    if (t == 0) atomicAdd(&acc[c], 1.f);
  }
  __syncthreads();
  for (int cc = t; cc < 820; cc += 256)
    A820[(size_t)r*820 + cc] = (cc == r) ? 0.f : acc[perm[cc]];
}

// dense level augment+pool: out[r,c] = (A^2)[pr,pc] + 2*A[pr,pc]  (r!=c), 0 on diag; A has zero diag
__global__ void k_augpool(const float* __restrict__ A, int n, const int* __restrict__ perm,
                          int knext, float* __restrict__ out) {
  __shared__ float rowb[832];
  int r = blockIdx.x, t = threadIdx.x;
  int pr = perm[r];
  for (int i = t; i < n; i += 256) rowb[i] = A[(size_t)pr*n + i];
  __syncthreads();
  for (int c = t; c < knext; c += 256) {
    int pc = perm[c];
    float dot = 0.f;
    for (int kk = 0; kk < n; kk++) {
      float rv = rowb[kk];
      if (rv != 0.f) dot += rv * A[(size_t)kk*n + pc];
    }
    out[(size_t)r*knext + c] = (c == r) ? 0.f : (dot + 2.f * rowb[pc]);
  }
}

__global__ void k_rowsum_dinv(const float* __restrict__ A, int n, float fill, float* __restrict__ dv) {
  __shared__ float red[256];
  int r = blockIdx.x, t = threadIdx.x;
  float s = 0.f;
  for (int c = t; c < n; c += 256) s += A[(size_t)r*n + c];
  red[t] = s; __syncthreads();
  for (int off = 128; off > 0; off >>= 1) { if (t < off) red[t] += red[t+off]; __syncthreads(); }
  if (t == 0) dv[r] = 1.f / sqrtf(red[0] + fill);
}

// dense GCN apply: out[i,:] = dinv_i*(sum_k A[i,k]*ts[k,:] + fill*ts[i,:]) + b (+relu)
__global__ void k_dense_gcn(const float* __restrict__ A, int n, const float* __restrict__ ts,
                            const float* __restrict__ dinv, float fill, const float* __restrict__ bias,
                            int relu, float* __restrict__ out) {
  __shared__ float arow[128];
  int i = blockIdx.x, t = threadIdx.x;
  float acc = 0.f;
  for (int k0 = 0; k0 < n; k0 += H) {
    int m = (n - k0 < H) ? (n - k0) : H;
    if (t < m) arow[t] = A[(size_t)i*n + k0 + t];
    __syncthreads();
    for (int kk = 0; kk < m; kk++) {
      float a = arow[kk]; // uniform across block -> uniform branch
      if (a != 0.f) acc += a * ts[(size_t)(k0 + kk)*H + t];
    }
    __syncthreads();
  }
  float v = dinv[i] * (acc + fill * ts[(size_t)i*H + t]) + bias[t];
  if (relu) v = fmaxf(v, 0.f);
  out[(size_t)i*H + t] = v;
}

__global__ void k_scatter_add(float* __restrict__ tmp, const int* __restrict__ perm,
                              const float* __restrict__ xc) {
  int r = blockIdx.x, t = threadIdx.x;
  tmp[(size_t)perm[r]*H + t] += xc[(size_t)r*H + t];
}

__global__ void k_relu(const float* __restrict__ x, float* __restrict__ y, int count) {
  int i = blockIdx.x * 256 + threadIdx.x;
  if (i < count) y[i] = fmaxf(x[i], 0.f);
}

// ts2[row,0:4] = dinv1_row * (cat([h1,h2r]) @ Wout)[row,:]
__global__ void k_outproj(const float* __restrict__ h1, const float* __restrict__ h2r,
                          const float* __restrict__ Wout, const float* __restrict__ dinv1,
                          float* __restrict__ ts2) {
  int row = blockIdx.x, t = threadIdx.x; // 64 threads
  float p0 = 0.f, p1 = 0.f, p2 = 0.f, p3 = 0.f;
#pragma unroll
  for (int half = 0; half < 2; half++) {
    float a = h1[(size_t)row*H + half*64 + t];
    const float* w = Wout + (half*64 + t)*4;
    p0 += a*w[0]; p1 += a*w[1]; p2 += a*w[2]; p3 += a*w[3];
    float b = h2r[(size_t)row*H + half*64 + t];
    const float* w2 = Wout + (128 + half*64 + t)*4;
    p0 += b*w2[0]; p1 += b*w2[1]; p2 += b*w2[2]; p3 += b*w2[3];
  }
  for (int off = 32; off > 0; off >>= 1) {
    p0 += __shfl_down(p0, off); p1 += __shfl_down(p1, off);
    p2 += __shfl_down(p2, off); p3 += __shfl_down(p3, off);
  }
  if (t == 0) {
    float d = dinv1[row];
    ts2[row*4+0] = d*p0; ts2[row*4+1] = d*p1; ts2[row*4+2] = d*p2; ts2[row*4+3] = d*p3;
  }
}

__global__ void k_gcn_out(const float* __restrict__ ts2, const int* __restrict__ rp,
                          const int* __restrict__ cols, const float* __restrict__ dinv1,
                          const float* __restrict__ bout, float* __restrict__ Fcur,
                          float* __restrict__ dout, int tstep) {
  int i = blockIdx.x, t = threadIdx.x; // 64 threads
  int f = t & 3;
  float acc = 0.f;
  int beg = rp[i], end = rp[i+1];
  for (int e = beg + (t >> 2); e < end; e += 16) acc += ts2[cols[e]*4 + f];
  for (int off = 32; off >= 4; off >>= 1) acc += __shfl_down(acc, off);
  if (t < 4) {
    float v = dinv1[i] * (acc + ts2[i*4 + f]) + bout[f];
    Fcur[i*4 + f] = v;
    dout[i*(NT*NF) + tstep*NF + f] = v;
  }
}

extern "C" void kernel_launch(void* const* d_in, const int* in_sizes, int n_in,
                              void* d_out, int out_size, void* d_ws, size_t ws_size,
                              hipStream_t stream) {
  const float* F0        = (const float*)d_in[0];
  const float* mesh_node = (const float*)d_in[1];
  const float* mesh_edge = (const float*)d_in[2];
  const float* Wm        = (const float*)d_in[3];
  const float* bm        = (const float*)d_in[4];
  const float* Wd0       = (const float*)d_in[5];
  const float* bd0       = (const float*)d_in[6];
  const float* Wd        = (const float*)d_in[7];
  const float* bd        = (const float*)d_in[8];
  const float* pool_w    = (const float*)d_in[9];
  const float* Wu        = (const float*)d_in[10];
  const float* bu        = (const float*)d_in[11];
  const float* Wout      = (const float*)d_in[12];
  const float* bout      = (const float*)d_in[13];
  const int*   ei        = (const int*)d_in[14];
  float* out = (float*)d_out;

  char* p = (char*)d_ws;
  auto carve = [&](size_t bytes) -> char* {
    char* r = p;
    p += (bytes + 255) & ~(size_t)255;
    return r;
  };
  int*   cnt    = (int*)carve((size_t)NN*4);
  int*   rp     = (int*)carve((size_t)(NN+1)*4);
  int*   cursor = (int*)carve((size_t)NN*4);
  int*   cols   = (int*)carve((size_t)EE*4);
  int*   permb  = (int*)carve((size_t)5*832*4);
  float* svb    = (float*)carve((size_t)5*832*4);
  float* dinv2  = (float*)carve((size_t)NN*4);
  float* dinv1  = (float*)carve((size_t)NN*4);
  float* pwn    = (float*)carve(8*4);
  float* S      = (float*)carve((size_t)NN*MEDGE*4);
  float* na     = (float*)carve((size_t)NN*140*4);
  float* P      = (float*)carve((size_t)NN*H*4);
  float* Q      = (float*)carve((size_t)NN*H*4);
  float* h1     = (float*)carve((size_t)NN*H*4);
  float* hbuf   = (float*)carve((size_t)NN*H*4);
  float* h2r    = (float*)carve((size_t)NN*H*4);
  float* tsb    = (float*)carve((size_t)NN*H*4);
  float* tmp    = (float*)carve((size_t)NN*H*4);   // also AQ scratch
  float* x0     = (float*)carve((size_t)NN*H*4);
  float* x1     = (float*)carve((size_t)820*H*4);
  float* x2     = (float*)carve((size_t)164*H*4);
  float* x3     = (float*)carve((size_t)33*H*4);
  float* x4     = (float*)carve((size_t)7*H*4);
  float* xp     = (float*)carve((size_t)820*H*4);
  float* xcur   = (float*)carve((size_t)820*H*4);
  float* score  = (float*)carve((size_t)NN*4);
  float* A820   = (float*)carve((size_t)820*820*4);
  float* A164   = (float*)carve((size_t)164*164*4);
  float* A33    = (float*)carve((size_t)33*33*4);
  float* A7     = (float*)carve((size_t)7*7*4);
  float* A2b    = (float*)carve((size_t)2*2*4);
  float* dv820  = (float*)carve(820*4);
  float* dv164  = (float*)carve(164*4);
  float* dv33   = (float*)carve(33*4);
  float* dv7    = (float*)carve(7*4);
  float* dv2    = (float*)carve(2*4);
  float* ts2    = (float*)carve((size_t)NN*NF*4);
  float* Fcur   = (float*)carve((size_t)NN*NF*4);

  const int KLh[5]  = {820, 164, 33, 7, 2};
  const int NPW[5]  = {4096, 1024, 256, 64, 8};
  const int szs[5]  = {4096, 820, 164, 33, 7};
  float* Adense[5] = {A820, A164, A33, A7, A2b};
  float* dvl[5]    = {dv820, dv164, dv33, dv7, dv2};
  float* xsv[5]    = {x0, x1, x2, x3, x4};
  int* perml[5]; float* svl[5];
  for (int l = 0; l < 5; l++) { perml[l] = permb + l*832; svl[l] = svb + l*832; }

  // ---- setup (once per launch) ----
  hipMemsetAsync(cnt, 0, (size_t)NN*4, stream);
  hipMemsetAsync(S, 0, (size_t)NN*MEDGE*4, stream);
  hipMemsetAsync(hbuf, 0, (size_t)NN*H*4, stream);
  k_count<<<EE/256, 256, 0, stream>>>(ei + EE, cnt);
  k_scan<<<1, 1024, 0, stream>>>(cnt, rp);
  hipMemcpyAsync(cursor, rp, (size_t)NN*4, hipMemcpyDeviceToDevice, stream);
  k_fill<<<EE/256, 256, 0, stream>>>(ei, cursor, cols);
  k_dinv0<<<NN/256, 256, 0, stream>>>(cnt, dinv2, dinv1);
  k_pwnorm<<<5, 64, 0, stream>>>(pool_w, pwn);
  k_segS<<<EE/256, 256, 0, stream>>>(ei + EE, mesh_edge, S);
  hipMemcpyAsync(Fcur, F0, (size_t)NN*NF*4, hipMemcpyDeviceToDevice, stream);

  for (int step = 0; step < NT; step++) {
    // edge MLP (factored) -> h1
    k_na<<<(NN*140 + 255)/256, 256, 0, stream>>>(Fcur, mesh_node, hbuf, na);
    k_mm_rb<<<NN, 128, 0, stream>>>(na, 140, Wm, P, 140, nullptr);
    k_mm_rb<<<NN, 128, 0, stream>>>(na, 140, Wm + 140*H, Q, 140, nullptr);
    k_spmm_fused<<<NN, 128, 0, stream>>>(Q, rp, cols, nullptr, 0.f, nullptr, 0, tmp); // AQ
    k_h1<<<NN, 128, 0, stream>>>(P, bm, tmp, S, Wm + 280*H, cnt, h1);

    // down GCN0 at 4096 (fill=2), relu
    k_mm_rb<<<NN, 128, 0, stream>>>(h1, H, Wd0, tsb, H, dinv2);
    k_spmm_fused<<<NN, 128, 0, stream>>>(tsb, rp, cols, dinv2, 2.f, bd0, 1, x0);

    // down path
    for (int i = 0; i < 5; i++) {
      int n_prev = szs[i], k = KLh[i];
      k_score<<<n_prev, 64, 0, stream>>>(xsv[i], pool_w + i*H, pwn + i, score);
      k_sort<<<1, 1024, 0, stream>>>(score, n_prev, NPW[i], k, perml[i], svl[i]);
      k_poolx<<<k, 128, 0, stream>>>(xsv[i], perml[i], svl[i], xp);
      if (i == 0) k_a820<<<820, 256, 0, stream>>>(rp, cols, perml[0], Adense[0]);
      else        k_augpool<<<k, 256, 0, stream>>>(Adense[i-1], n_prev, perml[i], k, Adense[i]);
      k_rowsum_dinv<<<k, 256, 0, stream>>>(Adense[i], k, 2.f, dvl[i]);
      k_mm_rb<<<k, 128, 0, stream>>>(xp, H, Wd + i*H*H, tsb, H, dvl[i]);
      float* outx = (i < 4) ? xsv[i+1] : xcur;
      k_dense_gcn<<<k, 128, 0, stream>>>(Adense[i], k, tsb, dvl[i], 2.f, bd + i*H, 1, outx);
    }

    // up path
    for (int i = 0; i < 5; i++) {
      int j = 4 - i;
      int n = szs[j], kk = KLh[j];
      hipMemcpyAsync(tmp, xsv[j], (size_t)n*H*4, hipMemcpyDeviceToDevice, stream);
      k_scatter_add<<<kk, 128, 0, stream>>>(tmp, perml[j], xcur);
      if (j > 0) {
        k_mm_rb<<<n, 128, 0, stream>>>(tmp, H, Wu + i*H*H, tsb, H, dvl[j-1]);
        k_dense_gcn<<<n, 128, 0, stream>>>(Adense[j-1], n, tsb, dvl[j-1], 2.f, bu + i*H,
                                           (i < 4) ? 1 : 0, xcur);
      } else {
        k_mm_rb<<<n, 128, 0, stream>>>(tmp, H, Wu + i*H*H, tsb, H, dinv2);
        k_spmm_fused<<<n, 128, 0, stream>>>(tsb, rp, cols, dinv2, 2.f, bu + i*H, 0, hbuf);
      }
    }

    // output GCN (fill=1)
    k_relu<<<(NN*H + 255)/256, 256, 0, stream>>>(hbuf, h2r, NN*H);
    k_outproj<<<NN, 64, 0, stream>>>(h1, h2r, Wout, dinv1, ts2);
    k_gcn_out<<<NN, 64, 0, stream>>>(ts2, rp, cols, dinv1, bout, Fcur, out, step);
  }
}

// Round 2
// 1395.985 us; speedup vs baseline: 1.0408x; 1.0408x over previous
//
#include <hip/hip_runtime.h>
#include <math.h>

#define NN 4096
#define EE 65536
#define H 128
#define NF 4
#define MNODE 8
#define MEDGE 4
#define NT 2

// ---------------- CSR build ----------------
__global__ void k_count(const int* __restrict__ dst, int* __restrict__ cnt) {
  int e = blockIdx.x * 256 + threadIdx.x;
  if (e < EE) atomicAdd(&cnt[dst[e]], 1);
}

__global__ void k_scan(const int* __restrict__ cnt, int* __restrict__ rp) {
  __shared__ int sh[1024];
  int t = threadIdx.x;
  int v0 = cnt[4*t], v1 = cnt[4*t+1], v2 = cnt[4*t+2], v3 = cnt[4*t+3];
  int p1 = v0, p2 = v0 + v1, p3 = p2 + v2, tot = p3 + v3;
  sh[t] = tot; __syncthreads();
  for (int off = 1; off < 1024; off <<= 1) {
    int add = (t >= off) ? sh[t-off] : 0;
    __syncthreads();
    sh[t] += add;
    __syncthreads();
  }
  int base = sh[t] - tot;
  rp[4*t] = base; rp[4*t+1] = base + p1; rp[4*t+2] = base + p2; rp[4*t+3] = base + p3;
  if (t == 1023) rp[NN] = sh[t];
}

__global__ void k_fill(const int* __restrict__ ei, int* __restrict__ cursor, int* __restrict__ cols) {
  int e = blockIdx.x * 256 + threadIdx.x;
  if (e < EE) {
    int d = ei[EE + e], s = ei[e];
    int pos = atomicAdd(&cursor[d], 1);
    cols[pos] = s;
  }
}

__global__ void k_dinv0(const int* __restrict__ cnt, float* __restrict__ d2, float* __restrict__ d1) {
  int i = blockIdx.x * 256 + threadIdx.x;
  if (i < NN) {
    float c = (float)cnt[i];
    d2[i] = 1.f / sqrtf(c + 2.f);
    d1[i] = 1.f / sqrtf(c + 1.f);
  }
}

__global__ void k_pwnorm(const float* __restrict__ pw, float* __restrict__ pwn) {
  int l = blockIdx.x, t = threadIdx.x; // 64 threads
  float a = pw[l*H + t], b = pw[l*H + 64 + t];
  float s = a*a + b*b;
  for (int off = 32; off > 0; off >>= 1) s += __shfl_down(s, off);
  if (t == 0) pwn[l] = sqrtf(s);
}

__global__ void k_segS(const int* __restrict__ dst, const float* __restrict__ me, float* __restrict__ S) {
  int e = blockIdx.x * 256 + threadIdx.x;
  if (e < EE) {
    int d = dst[e];
#pragma unroll
    for (int m = 0; m < MEDGE; m++) atomicAdd(&S[d*MEDGE + m], me[e*MEDGE + m]);
  }
}

// ---------------- node_attr & matmuls ----------------
__global__ void k_na(const float* __restrict__ F, const float* __restrict__ mn,
                     const float* __restrict__ h, float* __restrict__ na) {
  int idx = blockIdx.x * 256 + threadIdx.x;
  if (idx >= NN * 140) return;
  int row = idx / 140, c = idx - row * 140;
  float v;
  if (c < NF) v = F[row*NF + c];
  else if (c < NF + MNODE) v = mn[row*MNODE + (c - NF)];
  else v = h[row*H + (c - NF - MNODE)];
  na[idx] = v;
}

// C[row,0:128] = A[row,:K] @ B[:K,0:128]  (B row-stride 128); optional row scale by dinv
__global__ void k_mm_rb(const float* __restrict__ A, int lda, const float* __restrict__ B,
                        float* __restrict__ C, int K, const float* __restrict__ dinv) {
  __shared__ float as[160];
  int row = blockIdx.x, t = threadIdx.x;
  float acc = 0.f;
  for (int k0 = 0; k0 < K; k0 += H) {
    int m = (K - k0 < H) ? (K - k0) : H;
    if (t < m) as[t] = A[(size_t)row*lda + k0 + t];
    __syncthreads();
    for (int kk = 0; kk < m; kk++) acc += as[kk] * B[(k0 + kk)*H + t];
    __syncthreads();
  }
  if (dinv) acc *= dinv[row];
  C[(size_t)row*H + t] = acc;
}

// SpMM over CSR rows; if dinv!=null apply GCN epilogue: dinv_i*(acc + fill*ts_i) + bias (+relu)
__global__ void k_spmm_fused(const float* __restrict__ ts, const int* __restrict__ rp,
                             const int* __restrict__ cols, const float* __restrict__ dinv,
                             float fill, const float* __restrict__ bias, int relu,
                             float* __restrict__ out) {
  int i = blockIdx.x, t = threadIdx.x;
  float acc = 0.f;
  int beg = rp[i], end = rp[i+1];
  for (int e = beg; e < end; e++) acc += ts[(size_t)cols[e]*H + t];
  float v;
  if (dinv) {
    v = dinv[i] * (acc + fill * ts[(size_t)i*H + t]) + bias[t];
    if (relu) v = fmaxf(v, 0.f);
  } else v = acc;
  out[(size_t)i*H + t] = v;
}

__global__ void k_h1(const float* __restrict__ P, const float* __restrict__ bm,
                     const float* __restrict__ AQ, const float* __restrict__ S,
                     const float* __restrict__ WmB, const int* __restrict__ cnt,
                     float* __restrict__ h1) {
  int i = blockIdx.x, t = threadIdx.x;
  float v = (float)cnt[i] * (P[(size_t)i*H + t] + bm[t]) + AQ[(size_t)i*H + t];
#pragma unroll
  for (int m = 0; m < MEDGE; m++) v += S[i*MEDGE + m] * WmB[m*H + t];
  h1[(size_t)i*H + t] = fmaxf(v, 0.f);
}

// ---------------- top-k pooling ----------------
__global__ void k_score(const float* __restrict__ x, const float* __restrict__ pw,
                        const float* __restrict__ pwn, float* __restrict__ score) {
  int row = blockIdx.x, t = threadIdx.x; // 64 threads
  float s = x[(size_t)row*H + t]*pw[t] + x[(size_t)row*H + 64 + t]*pw[64 + t];
  for (int off = 32; off > 0; off >>= 1) s += __shfl_down(s, off);
  if (t == 0) score[row] = tanhf(s / pwn[0]);
}

// rank-based exact top-k (matches jax.lax.top_k: descending, ties -> lower index).
// Unique 64-bit key per element: (sortable(score) << 12) | (4095 - i).
// Output position of element i == its rank == #{j : key_j > key_i}.
__global__ void k_rank(const float* __restrict__ score, int n, int k,
                       int* __restrict__ perm, float* __restrict__ sv) {
  __shared__ unsigned long long keys[4096];
  int t = threadIdx.x;
  for (int i = t; i < n; i += 256) {
    float s = score[i] + 0.0f;              // canonicalize -0.0 -> +0.0
    unsigned u = __float_as_uint(s);
    u ^= (unsigned)(((int)u >> 31)) | 0x80000000u;  // ascending-sortable
    keys[i] = ((unsigned long long)u << 12) | (unsigned)(4095 - i);
  }
  __syncthreads();
  int i = blockIdx.x * 256 + t;
  if (i >= n) return;
  unsigned long long ki = keys[i];
  int r = 0;
#pragma unroll 4
  for (int j = 0; j < n; j++) r += (keys[j] > ki) ? 1 : 0;
  if (r < k) {
    perm[r] = i;
    sv[r] = score[i];
  }
}

__global__ void k_poolx(const float* __restrict__ x, const int* __restrict__ perm,
                        const float* __restrict__ sv, float* __restrict__ xp) {
  int r = blockIdx.x, t = threadIdx.x;
  xp[(size_t)r*H + t] = x[(size_t)perm[r]*H + t] * sv[r];
}

// A_820[r,c] = (A1@A1)[perm_r, perm_c], diag zeroed; A1 = offdiag(A0)+I via CSR
__global__ void k_a820(const int* __restrict__ rp, const int* __restrict__ cols,
                       const int* __restrict__ perm, float* __restrict__ A820) {
  __shared__ float acc[NN];
  int r = blockIdx.x, t = threadIdx.x;
  for (int i = t; i < NN; i += 256) acc[i] = 0.f;
  __syncthreads();
  int pi = perm[r];
  int beg = rp[pi], end = rp[pi+1];
  // k = pi term: + A1[pi,:]
  for (int e = beg + t; e < end; e += 256) { int c = cols[e]; if (c != pi) atomicAdd(&acc[c], 1.f); }
  if (t == 0) atomicAdd(&acc[pi], 1.f);
  // k != pi terms: for each off-diag edge instance (pi->c): + A1[c,:]
  for (int e0 = beg; e0 < end; e0++) {
    int c = cols[e0];
    if (c == pi) continue;
    int b2 = rp[c], e2 = rp[c+1];
    for (int e = b2 + t; e < e2; e += 256) { int c2 = cols[e]; if (c2 != c) atomicAdd(&acc[c2], 1.f); }
    if (t == 0) atomicAdd(&acc[c], 1.f);
  }
  __syncthreads();
  for (int cc = t; cc < 820; cc += 256)
    A820[(size_t)r*820 + cc] = (cc == r) ? 0.f : acc[perm[cc]];
}

// dense level augment+pool: out[r,c] = (A^2)[pr,pc] + 2*A[pr,pc]  (r!=c), 0 on diag; A has zero diag
__global__ void k_augpool(const float* __restrict__ A, int n, const int* __restrict__ perm,
                          int knext, float* __restrict__ out) {
  __shared__ float rowb[832];
  int r = blockIdx.x, t = threadIdx.x;
  int pr = perm[r];
  for (int i = t; i < n; i += 256) rowb[i] = A[(size_t)pr*n + i];
  __syncthreads();
  for (int c = t; c < knext; c += 256) {
    int pc = perm[c];
    float dot = 0.f;
    for (int kk = 0; kk < n; kk++) {
      float rv = rowb[kk];
      if (rv != 0.f) dot += rv * A[(size_t)kk*n + pc];
    }
    out[(size_t)r*knext + c] = (c == r) ? 0.f : (dot + 2.f * rowb[pc]);
  }
}

__global__ void k_rowsum_dinv(const float* __restrict__ A, int n, float fill, float* __restrict__ dv) {
  __shared__ float red[256];
  int r = blockIdx.x, t = threadIdx.x;
  float s = 0.f;
  for (int c = t; c < n; c += 256) s += A[(size_t)r*n + c];
  red[t] = s; __syncthreads();
  for (int off = 128; off > 0; off >>= 1) { if (t < off) red[t] += red[t+off]; __syncthreads(); }
  if (t == 0) dv[r] = 1.f / sqrtf(red[0] + fill);
}

// dense GCN apply: out[i,:] = dinv_i*(sum_k A[i,k]*ts[k,:] + fill*ts[i,:]) + b (+relu)
__global__ void k_dense_gcn(const float* __restrict__ A, int n, const float* __restrict__ ts,
                            const float* __restrict__ dinv, float fill, const float* __restrict__ bias,
                            int relu, float* __restrict__ out) {
  __shared__ float arow[128];
  int i = blockIdx.x, t = threadIdx.x;
  float acc = 0.f;
  for (int k0 = 0; k0 < n; k0 += H) {
    int m = (n - k0 < H) ? (n - k0) : H;
    if (t < m) arow[t] = A[(size_t)i*n + k0 + t];
    __syncthreads();
    for (int kk = 0; kk < m; kk++) {
      float a = arow[kk]; // uniform across block -> uniform branch
      if (a != 0.f) acc += a * ts[(size_t)(k0 + kk)*H + t];
    }
    __syncthreads();
  }
  float v = dinv[i] * (acc + fill * ts[(size_t)i*H + t]) + bias[t];
  if (relu) v = fmaxf(v, 0.f);
  out[(size_t)i*H + t] = v;
}

__global__ void k_scatter_add(float* __restrict__ tmp, const int* __restrict__ perm,
                              const float* __restrict__ xc) {
  int r = blockIdx.x, t = threadIdx.x;
  tmp[(size_t)perm[r]*H + t] += xc[(size_t)r*H + t];
}

__global__ void k_relu(const float* __restrict__ x, float* __restrict__ y, int count) {
  int i = blockIdx.x * 256 + threadIdx.x;
  if (i < count) y[i] = fmaxf(x[i], 0.f);
}

// ts2[row,0:4] = dinv1_row * (cat([h1,h2r]) @ Wout)[row,:]
__global__ void k_outproj(const float* __restrict__ h1, const float* __restrict__ h2r,
                          const float* __restrict__ Wout, const float* __restrict__ dinv1,
                          float* __restrict__ ts2) {
  int row = blockIdx.x, t = threadIdx.x; // 64 threads
  float p0 = 0.f, p1 = 0.f, p2 = 0.f, p3 = 0.f;
#pragma unroll
  for (int half = 0; half < 2; half++) {
    float a = h1[(size_t)row*H + half*64 + t];
    const float* w = Wout + (half*64 + t)*4;
    p0 += a*w[0]; p1 += a*w[1]; p2 += a*w[2]; p3 += a*w[3];
    float b = h2r[(size_t)row*H + half*64 + t];
    const float* w2 = Wout + (128 + half*64 + t)*4;
    p0 += b*w2[0]; p1 += b*w2[1]; p2 += b*w2[2]; p3 += b*w2[3];
  }
  for (int off = 32; off > 0; off >>= 1) {
    p0 += __shfl_down(p0, off); p1 += __shfl_down(p1, off);
    p2 += __shfl_down(p2, off); p3 += __shfl_down(p3, off);
  }
  if (t == 0) {
    float d = dinv1[row];
    ts2[row*4+0] = d*p0; ts2[row*4+1] = d*p1; ts2[row*4+2] = d*p2; ts2[row*4+3] = d*p3;
  }
}

__global__ void k_gcn_out(const float* __restrict__ ts2, const int* __restrict__ rp,
                          const int* __restrict__ cols, const float* __restrict__ dinv1,
                          const float* __restrict__ bout, float* __restrict__ Fcur,
                          float* __restrict__ dout, int tstep) {
  int i = blockIdx.x, t = threadIdx.x; // 64 threads
  int f = t & 3;
  float acc = 0.f;
  int beg = rp[i], end = rp[i+1];
  for (int e = beg + (t >> 2); e < end; e += 16) acc += ts2[cols[e]*4 + f];
  for (int off = 32; off >= 4; off >>= 1) acc += __shfl_down(acc, off);
  if (t < 4) {
    float v = dinv1[i] * (acc + ts2[i*4 + f]) + bout[f];
    Fcur[i*4 + f] = v;
    dout[i*(NT*NF) + tstep*NF + f] = v;
  }
}

extern "C" void kernel_launch(void* const* d_in, const int* in_sizes, int n_in,
                              void* d_out, int out_size, void* d_ws, size_t ws_size,
                              hipStream_t stream) {
  const float* F0        = (const float*)d_in[0];
  const float* mesh_node = (const float*)d_in[1];
  const float* mesh_edge = (const float*)d_in[2];
  const float* Wm        = (const float*)d_in[3];
  const float* bm        = (const float*)d_in[4];
  const float* Wd0       = (const float*)d_in[5];
  const float* bd0       = (const float*)d_in[6];
  const float* Wd        = (const float*)d_in[7];
  const float* bd        = (const float*)d_in[8];
  const float* pool_w    = (const float*)d_in[9];
  const float* Wu        = (const float*)d_in[10];
  const float* bu        = (const float*)d_in[11];
  const float* Wout      = (const float*)d_in[12];
  const float* bout      = (const float*)d_in[13];
  const int*   ei        = (const int*)d_in[14];
  float* out = (float*)d_out;

  char* p = (char*)d_ws;
  auto carve = [&](size_t bytes) -> char* {
    char* r = p;
    p += (bytes + 255) & ~(size_t)255;
    return r;
  };
  int*   cnt    = (int*)carve((size_t)NN*4);
  int*   rp     = (int*)carve((size_t)(NN+1)*4);
  int*   cursor = (int*)carve((size_t)NN*4);
  int*   cols   = (int*)carve((size_t)EE*4);
  int*   permb  = (int*)carve((size_t)5*832*4);
  float* svb    = (float*)carve((size_t)5*832*4);
  float* dinv2  = (float*)carve((size_t)NN*4);
  float* dinv1  = (float*)carve((size_t)NN*4);
  float* pwn    = (float*)carve(8*4);
  float* S      = (float*)carve((size_t)NN*MEDGE*4);
  float* na     = (float*)carve((size_t)NN*140*4);
  float* P      = (float*)carve((size_t)NN*H*4);
  float* Q      = (float*)carve((size_t)NN*H*4);
  float* h1     = (float*)carve((size_t)NN*H*4);
  float* hbuf   = (float*)carve((size_t)NN*H*4);
  float* h2r    = (float*)carve((size_t)NN*H*4);
  float* tsb    = (float*)carve((size_t)NN*H*4);
  float* tmp    = (float*)carve((size_t)NN*H*4);   // also AQ scratch
  float* x0     = (float*)carve((size_t)NN*H*4);
  float* x1     = (float*)carve((size_t)820*H*4);
  float* x2     = (float*)carve((size_t)164*H*4);
  float* x3     = (float*)carve((size_t)33*H*4);
  float* x4     = (float*)carve((size_t)7*H*4);
  float* xp     = (float*)carve((size_t)820*H*4);
  float* xcur   = (float*)carve((size_t)820*H*4);
  float* score  = (float*)carve((size_t)NN*4);
  float* A820   = (float*)carve((size_t)820*820*4);
  float* A164   = (float*)carve((size_t)164*164*4);
  float* A33    = (float*)carve((size_t)33*33*4);
  float* A7     = (float*)carve((size_t)7*7*4);
  float* A2b    = (float*)carve((size_t)2*2*4);
  float* dv820  = (float*)carve(820*4);
  float* dv164  = (float*)carve(164*4);
  float* dv33   = (float*)carve(33*4);
  float* dv7    = (float*)carve(7*4);
  float* dv2    = (float*)carve(2*4);
  float* ts2    = (float*)carve((size_t)NN*NF*4);
  float* Fcur   = (float*)carve((size_t)NN*NF*4);

  const int KLh[5]  = {820, 164, 33, 7, 2};
  const int szs[5]  = {4096, 820, 164, 33, 7};
  float* Adense[5] = {A820, A164, A33, A7, A2b};
  float* dvl[5]    = {dv820, dv164, dv33, dv7, dv2};
  float* xsv[5]    = {x0, x1, x2, x3, x4};
  int* perml[5]; float* svl[5];
  for (int l = 0; l < 5; l++) { perml[l] = permb + l*832; svl[l] = svb + l*832; }

  // ---- setup (once per launch) ----
  hipMemsetAsync(cnt, 0, (size_t)NN*4, stream);
  hipMemsetAsync(S, 0, (size_t)NN*MEDGE*4, stream);
  hipMemsetAsync(hbuf, 0, (size_t)NN*H*4, stream);
  k_count<<<EE/256, 256, 0, stream>>>(ei + EE, cnt);
  k_scan<<<1, 1024, 0, stream>>>(cnt, rp);
  hipMemcpyAsync(cursor, rp, (size_t)NN*4, hipMemcpyDeviceToDevice, stream);
  k_fill<<<EE/256, 256, 0, stream>>>(ei, cursor, cols);
  k_dinv0<<<NN/256, 256, 0, stream>>>(cnt, dinv2, dinv1);
  k_pwnorm<<<5, 64, 0, stream>>>(pool_w, pwn);
  k_segS<<<EE/256, 256, 0, stream>>>(ei + EE, mesh_edge, S);
  hipMemcpyAsync(Fcur, F0, (size_t)NN*NF*4, hipMemcpyDeviceToDevice, stream);

  for (int step = 0; step < NT; step++) {
    // edge MLP (factored) -> h1
    k_na<<<(NN*140 + 255)/256, 256, 0, stream>>>(Fcur, mesh_node, hbuf, na);
    k_mm_rb<<<NN, 128, 0, stream>>>(na, 140, Wm, P, 140, nullptr);
    k_mm_rb<<<NN, 128, 0, stream>>>(na, 140, Wm + 140*H, Q, 140, nullptr);
    k_spmm_fused<<<NN, 128, 0, stream>>>(Q, rp, cols, nullptr, 0.f, nullptr, 0, tmp); // AQ
    k_h1<<<NN, 128, 0, stream>>>(P, bm, tmp, S, Wm + 280*H, cnt, h1);

    // down GCN0 at 4096 (fill=2), relu
    k_mm_rb<<<NN, 128, 0, stream>>>(h1, H, Wd0, tsb, H, dinv2);
    k_spmm_fused<<<NN, 128, 0, stream>>>(tsb, rp, cols, dinv2, 2.f, bd0, 1, x0);

    // down path
    for (int i = 0; i < 5; i++) {
      int n_prev = szs[i], k = KLh[i];
      k_score<<<n_prev, 64, 0, stream>>>(xsv[i], pool_w + i*H, pwn + i, score);
      k_rank<<<(n_prev + 255)/256, 256, 0, stream>>>(score, n_prev, k, perml[i], svl[i]);
      k_poolx<<<k, 128, 0, stream>>>(xsv[i], perml[i], svl[i], xp);
      if (i == 0) k_a820<<<820, 256, 0, stream>>>(rp, cols, perml[0], Adense[0]);
      else        k_augpool<<<k, 256, 0, stream>>>(Adense[i-1], n_prev, perml[i], k, Adense[i]);
      k_rowsum_dinv<<<k, 256, 0, stream>>>(Adense[i], k, 2.f, dvl[i]);
      k_mm_rb<<<k, 128, 0, stream>>>(xp, H, Wd + i*H*H, tsb, H, dvl[i]);
      float* outx = (i < 4) ? xsv[i+1] : xcur;
      k_dense_gcn<<<k, 128, 0, stream>>>(Adense[i], k, tsb, dvl[i], 2.f, bd + i*H, 1, outx);
    }

    // up path
    for (int i = 0; i < 5; i++) {
      int j = 4 - i;
      int n = szs[j], kk = KLh[j];
      hipMemcpyAsync(tmp, xsv[j], (size_t)n*H*4, hipMemcpyDeviceToDevice, stream);
      k_scatter_add<<<kk, 128, 0, stream>>>(tmp, perml[j], xcur);
      if (j > 0) {
        k_mm_rb<<<n, 128, 0, stream>>>(tmp, H, Wu + i*H*H, tsb, H, dvl[j-1]);
        k_dense_gcn<<<n, 128, 0, stream>>>(Adense[j-1], n, tsb, dvl[j-1], 2.f, bu + i*H,
                                           (i < 4) ? 1 : 0, xcur);
      } else {
        k_mm_rb<<<n, 128, 0, stream>>>(tmp, H, Wu + i*H*H, tsb, H, dinv2);
        k_spmm_fused<<<n, 128, 0, stream>>>(tsb, rp, cols, dinv2, 2.f, bu + i*H, 0, hbuf);
      }
    }

    // output GCN (fill=1)
    k_relu<<<(NN*H + 255)/256, 256, 0, stream>>>(hbuf, h2r, NN*H);
    k_outproj<<<NN, 64, 0, stream>>>(h1, h2r, Wout, dinv1, ts2);
    k_gcn_out<<<NN, 64, 0, stream>>>(ts2, rp, cols, dinv1, bout, Fcur, out, step);
  }
}